// Round 1
// baseline (1307.245 us; speedup 1.0000x reference)
//
#include <hip/hip_runtime.h>
#include <hip/hip_bf16.h>

#define D_ 128

typedef __attribute__((ext_vector_type(8))) short short8;
typedef __attribute__((ext_vector_type(4))) float f32x4;

static __device__ __forceinline__ float lrelu(float x) { return x > 0.f ? x : 0.01f * x; }
static __device__ __forceinline__ short f2bf(float f) {
    __hip_bfloat16 h = __float2bfloat16(f);
    return *reinterpret_cast<short*>(&h);
}

// ---------------- weight prep: f32 -> bf16, transposed, combined ----------------
// W0T [512n][512k], n<256 = Wn0 col n, n>=256 = We0 col n-256
// W1T [256n][256k], n<128 = Wn1 col n, n>=128 = We1 col n-128
__global__ void prep_weights(const float* __restrict__ Wn0, const float* __restrict__ We0,
                             const float* __restrict__ Wn1, const float* __restrict__ We1,
                             const float* __restrict__ bn0, const float* __restrict__ be0,
                             const float* __restrict__ bn1, const float* __restrict__ be1,
                             short* __restrict__ W0T, short* __restrict__ W1T,
                             float* __restrict__ b0c, float* __restrict__ b1c) {
    int i = blockIdx.x * 256 + threadIdx.x;
    if (i < 512 * 512) {
        int n = i >> 9, k = i & 511;
        float v = (n < 256) ? Wn0[k * 256 + n] : We0[k * 256 + (n - 256)];
        W0T[i] = f2bf(v);
        return;
    }
    int j = i - 512 * 512;
    if (j < 256 * 256) {
        int n = j >> 8, k = j & 255;
        float v = (n < 128) ? Wn1[k * 128 + n] : We1[k * 128 + (n - 128)];
        W1T[j] = f2bf(v);
        return;
    }
    int t = j - 256 * 256;
    if (t < 512) b0c[t] = (t < 256) ? bn0[t] : be0[t - 256];
    else if (t < 768) b1c[t - 512] = (t < 640) ? bn1[t - 512] : be1[t - 640];
}

// ---------------- per-graph segment sums ----------------
__global__ void seg_sum(const float* __restrict__ src, const int* __restrict__ counts,
                        int G, int rows, int chunk, float* __restrict__ out) {
    int c = threadIdx.x & 127;
    int half = threadIdx.x >> 7;
    int r0 = blockIdx.x * chunk + half;
    int rend = min(rows, blockIdx.x * chunk + chunk);
    int cum[16];
    int s = 0;
    for (int i = 0; i < G; i++) { s += counts[i]; cum[i] = s; }
    float acc = 0.f;
    int accg = -1;
    for (int r = r0; r < rend; r += 2) {
        int g = 0;
        for (int i = 0; i < G; i++) if (r >= cum[i]) g = i + 1;
        if (g != accg) {
            if (accg >= 0) atomicAdd(&out[accg * D_ + c], acc);
            acc = 0.f; accg = g;
        }
        acc += src[(long)r * D_ + c];
    }
    if (accg >= 0) atomicAdd(&out[accg * D_ + c], acc);
}

// ---------------- global-feature MLP (tiny, pure f32) ----------------
__global__ void global_mlp(const float* __restrict__ glbs, const float* __restrict__ sumn,
                           const float* __restrict__ sume,
                           const float* __restrict__ Wg, const float* __restrict__ bg,
                           const float* __restrict__ Wgn, const float* __restrict__ bgn,
                           const float* __restrict__ Wge, const float* __restrict__ bge,
                           const float* __restrict__ Wf, const float* __restrict__ bfv,
                           int G, float* __restrict__ outg) {
    __shared__ float s_tmp[8][384];
    int c = threadIdx.x;  // 128 threads
    for (int r = 0; r < G; r++) {
        float a0 = 0.f, a1 = 0.f, a2 = 0.f;
        for (int k = 0; k < 128; k++) {
            a0 += glbs[r * 128 + k] * Wg[k * 128 + c];
            a1 += sumn[r * 128 + k] * Wgn[k * 128 + c];
            a2 += sume[r * 128 + k] * Wge[k * 128 + c];
        }
        s_tmp[r][c]       = lrelu(a0 + bg[c]);
        s_tmp[r][128 + c] = lrelu(a1 + bgn[c]);
        s_tmp[r][256 + c] = lrelu(a2 + bge[c]);
    }
    __syncthreads();
    for (int r = 0; r < G; r++) {
        float a = 0.f;
        for (int k = 0; k < 384; k++) a += s_tmp[r][k] * Wf[k * 128 + c];
        outg[r * 128 + c] = lrelu(a + bfv[c]);
    }
}

// ---------------- the big fused per-edge MLP ----------------
// block = 128 edges, 512 threads = 8 waves (2 M x 4 N)
// layer1: X[128x512] @ W0c[512x512] -> H (bf16, LDS, swizzled)
// layer2: Hn[128x256]@Wn1 -> msgs (atomic scatter), He@We1 -> new_edges
__launch_bounds__(512, 2)
__global__ void edge_mlp(const float* __restrict__ nodes, const float* __restrict__ edges,
                         const float* __restrict__ glbs,
                         const int* __restrict__ senders, const int* __restrict__ receivers,
                         const int* __restrict__ n_edge, int G,
                         const short* __restrict__ W0T, const short* __restrict__ W1T,
                         const float* __restrict__ b0c, const float* __restrict__ b1c,
                         float* __restrict__ out_nodes, float* __restrict__ out_edges) {
    __shared__ __align__(16) char sH[128 * 1024];  // H [128 rows][512 cols] bf16, swizzled
    __shared__ int s_send[128], s_recv[128], s_gid[128];

    const int tid  = threadIdx.x;
    const int lane = tid & 63;
    const int wid  = tid >> 6;
    const int wm   = wid >> 2;   // 0..1 : 64-row slice
    const int wn   = wid & 3;    // 0..3 : 128-col slice (layer1)
    const int l15  = lane & 15;
    const int lk   = lane >> 4;  // 0..3
    const int base = blockIdx.x * 128;

    if (tid < 128) {
        int e = base + tid;
        s_send[tid] = senders[e];
        s_recv[tid] = receivers[e];
        int cum = 0, g = 0;
        for (int i = 0; i < G; i++) { cum += n_edge[i]; if (e >= cum) g = i + 1; }
        s_gid[tid] = g;
    }
    __syncthreads();

    // ---- layer 1 ----
    f32x4 acc[4][8];
#pragma unroll
    for (int mt = 0; mt < 4; ++mt)
#pragma unroll
        for (int nt = 0; nt < 8; ++nt) acc[mt][nt] = (f32x4){0.f, 0.f, 0.f, 0.f};

#pragma unroll
    for (int c = 0; c < 4; ++c) {  // concat chunk: sender | receiver | edge | global
        const float* srcp[4];
#pragma unroll
        for (int mt = 0; mt < 4; ++mt) {
            int lrow = wm * 64 + mt * 16 + l15;
            int r;
            const float* bp;
            if (c == 0)      { r = s_send[lrow];  bp = nodes; }
            else if (c == 1) { r = s_recv[lrow];  bp = nodes; }
            else if (c == 2) { r = base + lrow;   bp = edges; }
            else             { r = s_gid[lrow];   bp = glbs;  }
            srcp[mt] = bp + (long)r * D_;
        }
#pragma unroll
        for (int kt = 0; kt < 4; ++kt) {
            short8 af[4];
#pragma unroll
            for (int mt = 0; mt < 4; ++mt) {
                const float* p = srcp[mt] + kt * 32 + lk * 8;
                float4 v0 = *(const float4*)(p);
                float4 v1 = *(const float4*)(p + 4);
                short8 a;
                a[0] = f2bf(v0.x); a[1] = f2bf(v0.y); a[2] = f2bf(v0.z); a[3] = f2bf(v0.w);
                a[4] = f2bf(v1.x); a[5] = f2bf(v1.y); a[6] = f2bf(v1.z); a[7] = f2bf(v1.w);
                af[mt] = a;
            }
#pragma unroll
            for (int nt = 0; nt < 8; ++nt) {
                int nrow = wn * 128 + nt * 16 + l15;
                short8 bfr = *(const short8*)(W0T + (long)nrow * 512 + c * 128 + kt * 32 + lk * 8);
#pragma unroll
                for (int mt = 0; mt < 4; ++mt)
                    acc[mt][nt] = __builtin_amdgcn_mfma_f32_16x16x32_bf16(af[mt], bfr, acc[mt][nt], 0, 0, 0);
            }
        }
    }

    // bias + leaky + bf16 -> LDS (XOR swizzle on byte bits 4..6)
#pragma unroll
    for (int nt = 0; nt < 8; ++nt) {
        int col = wn * 128 + nt * 16 + l15;
        float bias = b0c[col];
#pragma unroll
        for (int mt = 0; mt < 4; ++mt) {
#pragma unroll
            for (int q = 0; q < 4; ++q) {
                int row = wm * 64 + mt * 16 + lk * 4 + q;
                float v = lrelu(acc[mt][nt][q] + bias);
                int off = row * 1024 + ((col * 2) ^ ((row & 7) << 4));
                *(short*)(sH + off) = f2bf(v);
            }
        }
    }
    __syncthreads();

    // ---- layer 2 ----
    const int branch = wn >> 1;  // 0 = node-msg, 1 = edge-update
    const int halfn  = wn & 1;
    f32x4 acc2[4][4];
#pragma unroll
    for (int mt = 0; mt < 4; ++mt)
#pragma unroll
        for (int nt = 0; nt < 4; ++nt) acc2[mt][nt] = (f32x4){0.f, 0.f, 0.f, 0.f};

#pragma unroll
    for (int kt = 0; kt < 8; ++kt) {
        short8 af[4];
#pragma unroll
        for (int mt = 0; mt < 4; ++mt) {
            int row = wm * 64 + mt * 16 + l15;
            int kbyte = (branch * 256 + kt * 32 + lk * 8) * 2;
            int off = row * 1024 + (kbyte ^ ((row & 7) << 4));
            af[mt] = *(const short8*)(sH + off);
        }
#pragma unroll
        for (int nt = 0; nt < 4; ++nt) {
            int ncl = halfn * 64 + nt * 16 + l15;
            short8 bfr = *(const short8*)(W1T + (long)(branch * 128 + ncl) * 256 + kt * 32 + lk * 8);
#pragma unroll
            for (int mt = 0; mt < 4; ++mt)
                acc2[mt][nt] = __builtin_amdgcn_mfma_f32_16x16x32_bf16(af[mt], bfr, acc2[mt][nt], 0, 0, 0);
        }
    }

    // epilogue
#pragma unroll
    for (int nt = 0; nt < 4; ++nt) {
        int ncl = halfn * 64 + nt * 16 + l15;
        float bias = b1c[branch * 128 + ncl];
#pragma unroll
        for (int mt = 0; mt < 4; ++mt) {
#pragma unroll
            for (int q = 0; q < 4; ++q) {
                int row = wm * 64 + mt * 16 + lk * 4 + q;
                float v = lrelu(acc2[mt][nt][q] + bias);
                if (branch == 0) {
                    atomicAdd(&out_nodes[(long)s_recv[row] * D_ + ncl], v);
                } else {
                    out_edges[(long)(base + row) * D_ + ncl] = v;
                }
            }
        }
    }
}

extern "C" void kernel_launch(void* const* d_in, const int* in_sizes, int n_in,
                              void* d_out, int out_size, void* d_ws, size_t ws_size,
                              hipStream_t stream) {
    const float* nodes     = (const float*)d_in[0];
    const float* edges     = (const float*)d_in[1];
    const float* glbs      = (const float*)d_in[2];
    const int*   senders   = (const int*)d_in[3];
    const int*   receivers = (const int*)d_in[4];
    const int*   n_node    = (const int*)d_in[5];
    const int*   n_edge    = (const int*)d_in[6];
    const float* Wn0 = (const float*)d_in[7];
    const float* bn0 = (const float*)d_in[8];
    const float* Wn1 = (const float*)d_in[9];
    const float* bn1 = (const float*)d_in[10];
    const float* We0 = (const float*)d_in[11];
    const float* be0 = (const float*)d_in[12];
    const float* We1 = (const float*)d_in[13];
    const float* be1 = (const float*)d_in[14];
    const float* Wgn = (const float*)d_in[15];
    const float* bgn = (const float*)d_in[16];
    const float* Wge = (const float*)d_in[17];
    const float* bge = (const float*)d_in[18];
    const float* Wg  = (const float*)d_in[19];
    const float* bg  = (const float*)d_in[20];
    const float* Wf  = (const float*)d_in[21];
    const float* bfv = (const float*)d_in[22];

    const int N = in_sizes[0] / 128;
    const int E = in_sizes[1] / 128;
    const int G = in_sizes[2] / 128;

    char*  ws   = (char*)d_ws;
    short* W0T  = (short*)(ws);             // 512*512*2 = 524288
    short* W1T  = (short*)(ws + 524288);    // 256*256*2 = 131072
    float* b0c  = (float*)(ws + 655360);    // 2048
    float* b1c  = (float*)(ws + 657408);    // 1024
    float* sumn = (float*)(ws + 658432);    // 4096
    float* sume = (float*)(ws + 662528);    // 4096

    float* out_nodes = (float*)d_out;
    float* out_edges = out_nodes + (long)N * 128;
    float* out_glb   = out_edges + (long)E * 128;

    hipMemsetAsync(out_nodes, 0, (size_t)N * 128 * sizeof(float), stream);
    hipMemsetAsync(sumn, 0, 8192, stream);

    prep_weights<<<1283, 256, 0, stream>>>(Wn0, We0, Wn1, We1, bn0, be0, bn1, be1,
                                           W0T, W1T, b0c, b1c);

    seg_sum<<<(N + 63) / 64, 256, 0, stream>>>(nodes, n_node, G, N, 64, sumn);
    seg_sum<<<(E + 511) / 512, 256, 0, stream>>>(edges, n_edge, G, E, 512, sume);

    edge_mlp<<<E / 128, 512, 0, stream>>>(nodes, edges, glbs, senders, receivers, n_edge, G,
                                          W0T, W1T, b0c, b1c, out_nodes, out_edges);

    global_mlp<<<1, 128, 0, stream>>>(glbs, sumn, sume, Wg, bg, Wgn, bgn, Wge, bge, Wf, bfv,
                                      G, out_glb);
}